// Round 2
// baseline (488.435 us; speedup 1.0000x reference)
//
#include <hip/hip_runtime.h>
#include <hip/hip_bf16.h>
#include <stdint.h>

typedef __bf16 bf16x8 __attribute__((ext_vector_type(8)));
typedef float  f32x4  __attribute__((ext_vector_type(4)));

#define IN_DIM  4096
#define OUT_DIM 4096
#define M_DIM   8192

#define AS1 __attribute__((address_space(1)))
#define AS3 __attribute__((address_space(3)))

static __device__ __forceinline__ void gload_lds16(const void* g, void* l) {
  __builtin_amdgcn_global_load_lds((const AS1 void*)g, (AS3 void*)l, 16, 0, 0);
}

// ---------------- Pass 1: decode trellis + row FWHT(4096) + SU * 1/64 ----------------
// One block per output row r. 8 sequences of 16 words each -> 4096 values.
// state_t & 1023 == last 5 two-bit codes packed big-endian-first; extract from a
// 64-bit window over (prev_word, word).
__global__ __launch_bounds__(256) void k_decode_fwht_row(
    const int* __restrict__ trellis, const float2* __restrict__ tlut,
    const float* __restrict__ SU, __hip_bfloat16* __restrict__ w)
{
  __shared__ float buf[4096];
  __shared__ int words[128];
  __shared__ float2 lut[1024];
  const int tid = threadIdx.x;
  const int r = blockIdx.x;

  if (tid < 128) words[tid] = trellis[r * 128 + tid];
  for (int i = tid; i < 1024; i += 256) lut[i] = tlut[i];
  __syncthreads();

  {
    const int t  = tid;              // code index 0..255 within each sequence
    const int wi = t >> 4;           // word index
    const int sh = 30 - 2 * (t & 15);
    const unsigned mask = (t < 4) ? ((1u << (2 * t + 2)) - 1u) : 1023u;
    #pragma unroll
    for (int s = 0; s < 8; ++s) {
      unsigned lo = (unsigned)words[s * 16 + wi];
      unsigned hi = wi ? (unsigned)words[s * 16 + wi - 1] : 0u;
      unsigned long long comb = ((unsigned long long)hi << 32) | (unsigned long long)lo;
      unsigned st = ((unsigned)(comb >> sh)) & mask;
      float2 v = lut[st];
      buf[s * 512 + 2 * t]     = v.x;
      buf[s * 512 + 2 * t + 1] = v.y;
    }
  }
  __syncthreads();

  // 12-stage in-LDS FWHT over 4096 elements (natural-order Hadamard butterflies).
  for (int h = 1; h < 4096; h <<= 1) {
    #pragma unroll
    for (int q = 0; q < 8; ++q) {
      int b = q * 256 + tid;                       // butterfly id 0..2047
      int i = ((b & ~(h - 1)) << 1) | (b & (h - 1));
      float a = buf[i], c = buf[i + h];
      buf[i]     = a + c;
      buf[i + h] = a - c;
    }
    __syncthreads();
  }

  for (int q = 0; q < 16; ++q) {
    int c = q * 256 + tid;
    w[(size_t)r * IN_DIM + c] = __float2bfloat16(buf[c] * SU[c] * 0.015625f);
  }
}

// ---------------- Pass 2a: FWHT64 over row-index low 6 bits (in place) ----------------
__global__ __launch_bounds__(256) void k_fwht64_lo(__hip_bfloat16* __restrict__ w)
{
  __shared__ float tile[64][65];
  const int tid = threadIdx.x;
  const int rb = blockIdx.y, cb = blockIdx.x;

  for (int q = 0; q < 16; ++q) {
    int idx = q * 256 + tid;
    int rr = idx >> 6, cc = idx & 63;
    tile[rr][cc] = __bfloat162float(w[(size_t)(rb * 64 + rr) * IN_DIM + cb * 64 + cc]);
  }
  __syncthreads();

  const int c = tid & 63, qf = tid >> 6;
  for (int h = 1; h < 64; h <<= 1) {
    #pragma unroll
    for (int u = 0; u < 8; ++u) {
      int b = qf * 8 + u;                          // butterfly 0..31
      int i = ((b & ~(h - 1)) << 1) | (b & (h - 1));
      float a = tile[i][c], d = tile[i + h][c];
      tile[i][c]     = a + d;
      tile[i + h][c] = a - d;
    }
    __syncthreads();
  }

  for (int q = 0; q < 16; ++q) {
    int idx = q * 256 + tid;
    int rr = idx >> 6, cc = idx & 63;
    w[(size_t)(rb * 64 + rr) * IN_DIM + cb * 64 + cc] = __float2bfloat16(tile[rr][cc]);
  }
}

// ---------------- Pass 2b: FWHT64 over row-index high 6 bits + SV * 1/64 ----------------
__global__ __launch_bounds__(256) void k_fwht64_hi(__hip_bfloat16* __restrict__ w,
                                                   const float* __restrict__ SV)
{
  __shared__ float tile[64][65];
  const int tid = threadIdx.x;
  const int r0 = blockIdx.y, cb = blockIdx.x;

  for (int q = 0; q < 16; ++q) {
    int idx = q * 256 + tid;
    int r1 = idx >> 6, cc = idx & 63;
    tile[r1][cc] = __bfloat162float(w[(size_t)(r0 + 64 * r1) * IN_DIM + cb * 64 + cc]);
  }
  __syncthreads();

  const int c = tid & 63, qf = tid >> 6;
  for (int h = 1; h < 64; h <<= 1) {
    #pragma unroll
    for (int u = 0; u < 8; ++u) {
      int b = qf * 8 + u;
      int i = ((b & ~(h - 1)) << 1) | (b & (h - 1));
      float a = tile[i][c], d = tile[i + h][c];
      tile[i][c]     = a + d;
      tile[i + h][c] = a - d;
    }
    __syncthreads();
  }

  for (int q = 0; q < 16; ++q) {
    int idx = q * 256 + tid;
    int r1 = idx >> 6, cc = idx & 63;
    int row = r0 + 64 * r1;
    w[(size_t)row * IN_DIM + cb * 64 + cc] =
        __float2bfloat16(tile[r1][cc] * SV[row] * 0.015625f);
  }
}

// ---------------- x fp32 -> bf16 ----------------
__global__ __launch_bounds__(256) void k_cvt_x(const float* __restrict__ x,
                                               __hip_bfloat16* __restrict__ xb)
{
  size_t i = ((size_t)blockIdx.x * 256 + threadIdx.x) * 8;
  float4 v0 = *(const float4*)(x + i);
  float4 v1 = *(const float4*)(x + i + 4);
  union { __hip_bfloat16 h[8]; uint4 u; } p;
  p.h[0] = __float2bfloat16(v0.x); p.h[1] = __float2bfloat16(v0.y);
  p.h[2] = __float2bfloat16(v0.z); p.h[3] = __float2bfloat16(v0.w);
  p.h[4] = __float2bfloat16(v1.x); p.h[5] = __float2bfloat16(v1.y);
  p.h[6] = __float2bfloat16(v1.z); p.h[7] = __float2bfloat16(v1.w);
  *(uint4*)(xb + i) = p.u;
}

// ---------------- GEMM: out[M][N] = Xb[M][K] * W[N][K]^T  (bf16 MFMA, fp32 acc) ----------------
#define BM 128
#define BN 128
#define BK 64

__global__ __launch_bounds__(256) void k_gemm(
    const __hip_bfloat16* __restrict__ X,   // [8192][4096]
    const __hip_bfloat16* __restrict__ W,   // [4096][4096]
    float* __restrict__ out)                // [8192][4096]
{
  __shared__ __align__(16) __hip_bfloat16 As[BM * BK];
  __shared__ __align__(16) __hip_bfloat16 Bs[BN * BK];

  const int tid  = threadIdx.x;
  const int lane = tid & 63;
  const int wave = tid >> 6;
  const int wm = wave >> 1, wn = wave & 1;
  const int m0 = blockIdx.y * BM;
  const int n0 = blockIdx.x * BN;
  const int K = IN_DIM;

  f32x4 acc[4][4] = {};

  for (int k0 = 0; k0 < K; k0 += BK) {
    __syncthreads();   // previous compute done before LDS overwrite
    // Stage A tile: 128x64 bf16 = 16 KB = 4 issues x 256 lanes x 16 B
    #pragma unroll
    for (int is = 0; is < 4; ++is) {
      int chunk = is * 256 + tid;          // 0..1023, 8 bf16 each
      int row = chunk >> 3, jj = chunk & 7;
      gload_lds16(X + (size_t)(m0 + row) * K + k0 + jj * 8, As + chunk * 8);
    }
    #pragma unroll
    for (int is = 0; is < 4; ++is) {
      int chunk = is * 256 + tid;
      int row = chunk >> 3, jj = chunk & 7;
      gload_lds16(W + (size_t)(n0 + row) * K + k0 + jj * 8, Bs + chunk * 8);
    }
    __syncthreads();   // compiler drains vmcnt before the barrier

    #pragma unroll
    for (int kk = 0; kk < 2; ++kk) {
      bf16x8 af[4], bfr[4];
      const int krow = kk * 32 + (lane >> 4) * 8;
      #pragma unroll
      for (int mi = 0; mi < 4; ++mi) {
        int rr = wm * 64 + mi * 16 + (lane & 15);
        af[mi] = *(const bf16x8*)(As + rr * BK + krow);
      }
      #pragma unroll
      for (int ni = 0; ni < 4; ++ni) {
        int rr = wn * 64 + ni * 16 + (lane & 15);
        bfr[ni] = *(const bf16x8*)(Bs + rr * BK + krow);
      }
      #pragma unroll
      for (int mi = 0; mi < 4; ++mi)
        #pragma unroll
        for (int ni = 0; ni < 4; ++ni)
          acc[mi][ni] = __builtin_amdgcn_mfma_f32_16x16x32_bf16(
              af[mi], bfr[ni], acc[mi][ni], 0, 0, 0);
    }
  }

  // Epilogue: C/D layout col = lane&15, row = (lane>>4)*4 + reg
  #pragma unroll
  for (int mi = 0; mi < 4; ++mi) {
    #pragma unroll
    for (int ni = 0; ni < 4; ++ni) {
      int col   = n0 + wn * 64 + ni * 16 + (lane & 15);
      int rbase = m0 + wm * 64 + mi * 16 + (lane >> 4) * 4;
      #pragma unroll
      for (int rg = 0; rg < 4; ++rg) {
        out[(size_t)(rbase + rg) * OUT_DIM + col] = acc[mi][ni][rg];
      }
    }
  }
}

extern "C" void kernel_launch(void* const* d_in, const int* in_sizes, int n_in,
                              void* d_out, int out_size, void* d_ws, size_t ws_size,
                              hipStream_t stream) {
  (void)in_sizes; (void)n_in; (void)out_size; (void)ws_size;
  const float* x       = (const float*)d_in[0];
  const int*   trellis = (const int*)d_in[1];
  const float* tlut    = (const float*)d_in[2];
  const float* SU      = (const float*)d_in[3];
  const float* SV      = (const float*)d_in[4];
  float* out = (float*)d_out;

  __hip_bfloat16* W  = (__hip_bfloat16*)d_ws;                                    // 32 MB
  __hip_bfloat16* Xb = (__hip_bfloat16*)((char*)d_ws + (size_t)32 * 1024 * 1024); // 64 MB

  k_decode_fwht_row<<<4096, 256, 0, stream>>>(trellis, (const float2*)tlut, SU, W);
  k_fwht64_lo<<<dim3(64, 64), 256, 0, stream>>>(W);
  k_fwht64_hi<<<dim3(64, 64), 256, 0, stream>>>(W, SV);
  k_cvt_x<<<16384, 256, 0, stream>>>(x, Xb);
  k_gemm<<<dim3(32, 64), 256, 0, stream>>>(Xb, W, out);
}

// Round 3
// 441.930 us; speedup vs baseline: 1.1052x; 1.1052x over previous
//
#include <hip/hip_runtime.h>
#include <hip/hip_bf16.h>
#include <stdint.h>

typedef __bf16 bf16x8 __attribute__((ext_vector_type(8)));
typedef float  f32x4  __attribute__((ext_vector_type(4)));

#define IN_DIM  4096
#define OUT_DIM 4096
#define M_DIM   8192

#define AS1 __attribute__((address_space(1)))
#define AS3 __attribute__((address_space(3)))

static __device__ __forceinline__ void gload_lds16(const void* g, void* l) {
  __builtin_amdgcn_global_load_lds((const AS1 void*)g, (AS3 void*)l, 16, 0, 0);
}

// ---------------- Pass 1: decode trellis + row FWHT(4096) + SU * 1/64 ----------------
__global__ __launch_bounds__(256) void k_decode_fwht_row(
    const int* __restrict__ trellis, const float2* __restrict__ tlut,
    const float* __restrict__ SU, __hip_bfloat16* __restrict__ w)
{
  __shared__ float buf[4096];
  __shared__ int words[128];
  __shared__ float2 lut[1024];
  const int tid = threadIdx.x;
  const int r = blockIdx.x;

  if (tid < 128) words[tid] = trellis[r * 128 + tid];
  for (int i = tid; i < 1024; i += 256) lut[i] = tlut[i];
  __syncthreads();

  {
    const int t  = tid;              // code index 0..255 within each sequence
    const int wi = t >> 4;           // word index
    const int sh = 30 - 2 * (t & 15);
    const unsigned mask = (t < 4) ? ((1u << (2 * t + 2)) - 1u) : 1023u;
    #pragma unroll
    for (int s = 0; s < 8; ++s) {
      unsigned lo = (unsigned)words[s * 16 + wi];
      unsigned hi = wi ? (unsigned)words[s * 16 + wi - 1] : 0u;
      unsigned long long comb = ((unsigned long long)hi << 32) | (unsigned long long)lo;
      unsigned st = ((unsigned)(comb >> sh)) & mask;
      float2 v = lut[st];
      buf[s * 512 + 2 * t]     = v.x;
      buf[s * 512 + 2 * t + 1] = v.y;
    }
  }
  __syncthreads();

  for (int h = 1; h < 4096; h <<= 1) {
    #pragma unroll
    for (int q = 0; q < 8; ++q) {
      int b = q * 256 + tid;                       // butterfly id 0..2047
      int i = ((b & ~(h - 1)) << 1) | (b & (h - 1));
      float a = buf[i], c = buf[i + h];
      buf[i]     = a + c;
      buf[i + h] = a - c;
    }
    __syncthreads();
  }

  for (int q = 0; q < 16; ++q) {
    int c = q * 256 + tid;
    w[(size_t)r * IN_DIM + c] = __float2bfloat16(buf[c] * SU[c] * 0.015625f);
  }
}

// ---------------- Pass 2a: FWHT64 over row-index low 6 bits (in place) ----------------
__global__ __launch_bounds__(256) void k_fwht64_lo(__hip_bfloat16* __restrict__ w)
{
  __shared__ float tile[64][65];
  const int tid = threadIdx.x;
  const int rb = blockIdx.y, cb = blockIdx.x;

  for (int q = 0; q < 16; ++q) {
    int idx = q * 256 + tid;
    int rr = idx >> 6, cc = idx & 63;
    tile[rr][cc] = __bfloat162float(w[(size_t)(rb * 64 + rr) * IN_DIM + cb * 64 + cc]);
  }
  __syncthreads();

  const int c = tid & 63, qf = tid >> 6;
  for (int h = 1; h < 64; h <<= 1) {
    #pragma unroll
    for (int u = 0; u < 8; ++u) {
      int b = qf * 8 + u;                          // butterfly 0..31
      int i = ((b & ~(h - 1)) << 1) | (b & (h - 1));
      float a = tile[i][c], d = tile[i + h][c];
      tile[i][c]     = a + d;
      tile[i + h][c] = a - d;
    }
    __syncthreads();
  }

  for (int q = 0; q < 16; ++q) {
    int idx = q * 256 + tid;
    int rr = idx >> 6, cc = idx & 63;
    w[(size_t)(rb * 64 + rr) * IN_DIM + cb * 64 + cc] = __float2bfloat16(tile[rr][cc]);
  }
}

// ---------------- Pass 2b: FWHT64 over row-index high 6 bits + SV * 1/64 ----------------
__global__ __launch_bounds__(256) void k_fwht64_hi(__hip_bfloat16* __restrict__ w,
                                                   const float* __restrict__ SV)
{
  __shared__ float tile[64][65];
  const int tid = threadIdx.x;
  const int r0 = blockIdx.y, cb = blockIdx.x;

  for (int q = 0; q < 16; ++q) {
    int idx = q * 256 + tid;
    int r1 = idx >> 6, cc = idx & 63;
    tile[r1][cc] = __bfloat162float(w[(size_t)(r0 + 64 * r1) * IN_DIM + cb * 64 + cc]);
  }
  __syncthreads();

  const int c = tid & 63, qf = tid >> 6;
  for (int h = 1; h < 64; h <<= 1) {
    #pragma unroll
    for (int u = 0; u < 8; ++u) {
      int b = qf * 8 + u;
      int i = ((b & ~(h - 1)) << 1) | (b & (h - 1));
      float a = tile[i][c], d = tile[i + h][c];
      tile[i][c]     = a + d;
      tile[i + h][c] = a - d;
    }
    __syncthreads();
  }

  for (int q = 0; q < 16; ++q) {
    int idx = q * 256 + tid;
    int r1 = idx >> 6, cc = idx & 63;
    int row = r0 + 64 * r1;
    w[(size_t)row * IN_DIM + cb * 64 + cc] =
        __float2bfloat16(tile[r1][cc] * SV[row] * 0.015625f);
  }
}

// ---------------- x fp32 -> bf16 ----------------
__global__ __launch_bounds__(256) void k_cvt_x(const float* __restrict__ x,
                                               __hip_bfloat16* __restrict__ xb)
{
  size_t i = ((size_t)blockIdx.x * 256 + threadIdx.x) * 8;
  float4 v0 = *(const float4*)(x + i);
  float4 v1 = *(const float4*)(x + i + 4);
  union { __hip_bfloat16 h[8]; uint4 u; } p;
  p.h[0] = __float2bfloat16(v0.x); p.h[1] = __float2bfloat16(v0.y);
  p.h[2] = __float2bfloat16(v0.z); p.h[3] = __float2bfloat16(v0.w);
  p.h[4] = __float2bfloat16(v1.x); p.h[5] = __float2bfloat16(v1.y);
  p.h[6] = __float2bfloat16(v1.z); p.h[7] = __float2bfloat16(v1.w);
  *(uint4*)(xb + i) = p.u;
}

// ---------------- GEMM: out[M][N] = Xb[M][K] * W[N][K]^T  (bf16 MFMA, fp32 acc) ----------------
// T2 XOR-swizzled LDS (byte ^= (row&7)<<4), realized per rule #21 as:
//   linear LDS dest for global_load_lds + inverse-swizzled GLOBAL source + swizzled ds_read.
#define BM 128
#define BN 128
#define BK 64

__global__ __launch_bounds__(256) void k_gemm(
    const __hip_bfloat16* __restrict__ X,   // [8192][4096]
    const __hip_bfloat16* __restrict__ W,   // [4096][4096]
    float* __restrict__ out)                // [8192][4096]
{
  __shared__ __align__(16) __hip_bfloat16 As[BM * BK];
  __shared__ __align__(16) __hip_bfloat16 Bs[BN * BK];

  const int tid  = threadIdx.x;
  const int lane = tid & 63;
  const int wave = tid >> 6;
  const int wm = wave >> 1, wn = wave & 1;

  // T1: bijective XCD-aware swizzle of the 2048-block grid (2048 % 8 == 0).
  const int nwg  = gridDim.x * gridDim.y;          // 2048
  const int cpx  = nwg >> 3;                       // 256 blocks per XCD chunk
  const int orig = blockIdx.y * gridDim.x + blockIdx.x;
  const int swz  = (orig & 7) * cpx + (orig >> 3);
  const int bx   = swz % gridDim.x;                // N-tile
  const int by   = swz / gridDim.x;                // M-tile
  const int m0 = by * BM;
  const int n0 = bx * BN;
  const int K = IN_DIM;

  f32x4 acc[4][4] = {};

  for (int k0 = 0; k0 < K; k0 += BK) {
    __syncthreads();   // previous compute done before LDS overwrite
    // Stage tiles: LDS chunk c (16 B) holds global chunk (row=c>>3, (c&7)^(row&7)).
    #pragma unroll
    for (int is = 0; is < 4; ++is) {
      int chunk = is * 256 + tid;          // 0..1023
      int row = chunk >> 3;
      int jj  = (chunk & 7) ^ (row & 7);   // inverse-swizzled source chunk
      gload_lds16(X + (size_t)(m0 + row) * K + k0 + jj * 8, As + chunk * 8);
    }
    #pragma unroll
    for (int is = 0; is < 4; ++is) {
      int chunk = is * 256 + tid;
      int row = chunk >> 3;
      int jj  = (chunk & 7) ^ (row & 7);
      gload_lds16(W + (size_t)(n0 + row) * K + k0 + jj * 8, Bs + chunk * 8);
    }
    __syncthreads();

    #pragma unroll
    for (int kk = 0; kk < 2; ++kk) {
      bf16x8 af[4], bfr[4];
      const int q = kk * 4 + (lane >> 4);  // 16B col-chunk index (krow/8)
      #pragma unroll
      for (int mi = 0; mi < 4; ++mi) {
        int rr = wm * 64 + mi * 16 + (lane & 15);
        af[mi] = *(const bf16x8*)(As + rr * BK + ((q ^ (rr & 7)) << 3));
      }
      #pragma unroll
      for (int ni = 0; ni < 4; ++ni) {
        int rr = wn * 64 + ni * 16 + (lane & 15);
        bfr[ni] = *(const bf16x8*)(Bs + rr * BK + ((q ^ (rr & 7)) << 3));
      }
      #pragma unroll
      for (int mi = 0; mi < 4; ++mi)
        #pragma unroll
        for (int ni = 0; ni < 4; ++ni)
          acc[mi][ni] = __builtin_amdgcn_mfma_f32_16x16x32_bf16(
              af[mi], bfr[ni], acc[mi][ni], 0, 0, 0);
    }
  }

  // Epilogue: C/D layout col = lane&15, row = (lane>>4)*4 + reg
  #pragma unroll
  for (int mi = 0; mi < 4; ++mi) {
    #pragma unroll
    for (int ni = 0; ni < 4; ++ni) {
      int col   = n0 + wn * 64 + ni * 16 + (lane & 15);
      int rbase = m0 + wm * 64 + mi * 16 + (lane >> 4) * 4;
      #pragma unroll
      for (int rg = 0; rg < 4; ++rg) {
        out[(size_t)(rbase + rg) * OUT_DIM + col] = acc[mi][ni][rg];
      }
    }
  }
}

extern "C" void kernel_launch(void* const* d_in, const int* in_sizes, int n_in,
                              void* d_out, int out_size, void* d_ws, size_t ws_size,
                              hipStream_t stream) {
  (void)in_sizes; (void)n_in; (void)out_size; (void)ws_size;
  const float* x       = (const float*)d_in[0];
  const int*   trellis = (const int*)d_in[1];
  const float* tlut    = (const float*)d_in[2];
  const float* SU      = (const float*)d_in[3];
  const float* SV      = (const float*)d_in[4];
  float* out = (float*)d_out;

  __hip_bfloat16* W  = (__hip_bfloat16*)d_ws;                                    // 32 MB
  __hip_bfloat16* Xb = (__hip_bfloat16*)((char*)d_ws + (size_t)32 * 1024 * 1024); // 64 MB

  k_decode_fwht_row<<<4096, 256, 0, stream>>>(trellis, (const float2*)tlut, SU, W);
  k_fwht64_lo<<<dim3(64, 64), 256, 0, stream>>>(W);
  k_fwht64_hi<<<dim3(64, 64), 256, 0, stream>>>(W, SV);
  k_cvt_x<<<16384, 256, 0, stream>>>(x, Xb);
  k_gemm<<<dim3(32, 64), 256, 0, stream>>>(Xb, W, out);
}

// Round 4
// 376.678 us; speedup vs baseline: 1.2967x; 1.1732x over previous
//
#include <hip/hip_runtime.h>
#include <hip/hip_bf16.h>
#include <stdint.h>

typedef __bf16 bf16x8 __attribute__((ext_vector_type(8)));
typedef float  f32x4  __attribute__((ext_vector_type(4)));

#define IN_DIM  4096
#define OUT_DIM 4096
#define M_DIM   8192

#define AS1 __attribute__((address_space(1)))
#define AS3 __attribute__((address_space(3)))

static __device__ __forceinline__ void gload_lds16(const void* g, void* l) {
  __builtin_amdgcn_global_load_lds((const AS1 void*)g, (AS3 void*)l, 16, 0, 0);
}

// ---------------- Pass 1: decode trellis + row FWHT(4096) + SU * 1/64 ----------------
__global__ __launch_bounds__(256) void k_decode_fwht_row(
    const int* __restrict__ trellis, const float2* __restrict__ tlut,
    const float* __restrict__ SU, __hip_bfloat16* __restrict__ w)
{
  __shared__ float buf[4096];
  __shared__ int words[128];
  __shared__ float2 lut[1024];
  const int tid = threadIdx.x;
  const int r = blockIdx.x;

  if (tid < 128) words[tid] = trellis[r * 128 + tid];
  for (int i = tid; i < 1024; i += 256) lut[i] = tlut[i];
  __syncthreads();

  {
    const int t  = tid;
    const int wi = t >> 4;
    const int sh = 30 - 2 * (t & 15);
    const unsigned mask = (t < 4) ? ((1u << (2 * t + 2)) - 1u) : 1023u;
    #pragma unroll
    for (int s = 0; s < 8; ++s) {
      unsigned lo = (unsigned)words[s * 16 + wi];
      unsigned hi = wi ? (unsigned)words[s * 16 + wi - 1] : 0u;
      unsigned long long comb = ((unsigned long long)hi << 32) | (unsigned long long)lo;
      unsigned st = ((unsigned)(comb >> sh)) & mask;
      float2 v = lut[st];
      buf[s * 512 + 2 * t]     = v.x;
      buf[s * 512 + 2 * t + 1] = v.y;
    }
  }
  __syncthreads();

  for (int h = 1; h < 4096; h <<= 1) {
    #pragma unroll
    for (int q = 0; q < 8; ++q) {
      int b = q * 256 + tid;
      int i = ((b & ~(h - 1)) << 1) | (b & (h - 1));
      float a = buf[i], c = buf[i + h];
      buf[i]     = a + c;
      buf[i + h] = a - c;
    }
    __syncthreads();
  }

  for (int q = 0; q < 16; ++q) {
    int c = q * 256 + tid;
    w[(size_t)r * IN_DIM + c] = __float2bfloat16(buf[c] * SU[c] * 0.015625f);
  }
}

// ---------------- Pass 2a: FWHT64 over row-index low 6 bits (in place) ----------------
__global__ __launch_bounds__(256) void k_fwht64_lo(__hip_bfloat16* __restrict__ w)
{
  __shared__ float tile[64][65];
  const int tid = threadIdx.x;
  const int rb = blockIdx.y, cb = blockIdx.x;

  for (int q = 0; q < 16; ++q) {
    int idx = q * 256 + tid;
    int rr = idx >> 6, cc = idx & 63;
    tile[rr][cc] = __bfloat162float(w[(size_t)(rb * 64 + rr) * IN_DIM + cb * 64 + cc]);
  }
  __syncthreads();

  const int c = tid & 63, qf = tid >> 6;
  for (int h = 1; h < 64; h <<= 1) {
    #pragma unroll
    for (int u = 0; u < 8; ++u) {
      int b = qf * 8 + u;
      int i = ((b & ~(h - 1)) << 1) | (b & (h - 1));
      float a = tile[i][c], d = tile[i + h][c];
      tile[i][c]     = a + d;
      tile[i + h][c] = a - d;
    }
    __syncthreads();
  }

  for (int q = 0; q < 16; ++q) {
    int idx = q * 256 + tid;
    int rr = idx >> 6, cc = idx & 63;
    w[(size_t)(rb * 64 + rr) * IN_DIM + cb * 64 + cc] = __float2bfloat16(tile[rr][cc]);
  }
}

// ---------------- Pass 2b: FWHT64 over row-index high 6 bits + SV * 1/64 ----------------
__global__ __launch_bounds__(256) void k_fwht64_hi(__hip_bfloat16* __restrict__ w,
                                                   const float* __restrict__ SV)
{
  __shared__ float tile[64][65];
  const int tid = threadIdx.x;
  const int r0 = blockIdx.y, cb = blockIdx.x;

  for (int q = 0; q < 16; ++q) {
    int idx = q * 256 + tid;
    int r1 = idx >> 6, cc = idx & 63;
    tile[r1][cc] = __bfloat162float(w[(size_t)(r0 + 64 * r1) * IN_DIM + cb * 64 + cc]);
  }
  __syncthreads();

  const int c = tid & 63, qf = tid >> 6;
  for (int h = 1; h < 64; h <<= 1) {
    #pragma unroll
    for (int u = 0; u < 8; ++u) {
      int b = qf * 8 + u;
      int i = ((b & ~(h - 1)) << 1) | (b & (h - 1));
      float a = tile[i][c], d = tile[i + h][c];
      tile[i][c]     = a + d;
      tile[i + h][c] = a - d;
    }
    __syncthreads();
  }

  for (int q = 0; q < 16; ++q) {
    int idx = q * 256 + tid;
    int r1 = idx >> 6, cc = idx & 63;
    int row = r0 + 64 * r1;
    w[(size_t)row * IN_DIM + cb * 64 + cc] =
        __float2bfloat16(tile[r1][cc] * SV[row] * 0.015625f);
  }
}

// ---------------- x fp32 -> bf16 ----------------
__global__ __launch_bounds__(256) void k_cvt_x(const float* __restrict__ x,
                                               __hip_bfloat16* __restrict__ xb)
{
  size_t i = ((size_t)blockIdx.x * 256 + threadIdx.x) * 8;
  float4 v0 = *(const float4*)(x + i);
  float4 v1 = *(const float4*)(x + i + 4);
  union { __hip_bfloat16 h[8]; uint4 u; } p;
  p.h[0] = __float2bfloat16(v0.x); p.h[1] = __float2bfloat16(v0.y);
  p.h[2] = __float2bfloat16(v0.z); p.h[3] = __float2bfloat16(v0.w);
  p.h[4] = __float2bfloat16(v1.x); p.h[5] = __float2bfloat16(v1.y);
  p.h[6] = __float2bfloat16(v1.z); p.h[7] = __float2bfloat16(v1.w);
  *(uint4*)(xb + i) = p.u;
}

// ================= GEMM: 256x256 tile, 8-phase counted-vmcnt schedule =================
// out[M][N] = Xb[M][K] * W[N][K]^T, bf16 MFMA fp32 acc.
// 8 waves (2Mx4N), BK=64, LDS 128 KiB double-buffered, T2 swizzle, T5 setprio.
// Phase = {12 ds_read_b128 ; 2 global_load_lds ; s_barrier ; lgkmcnt(0) ; 16 MFMA ; [vmcnt(4)] ; s_barrier}.
// Region-safe staging: each phase stages exactly the LDS region whose last read
// retired before the previous end-of-phase barrier (see derivation in commit msg).
#define GBM 256
#define GBN 256
#define GBK 64
#define NT  (IN_DIM / GBK)   // 64 K-tiles

__global__ __launch_bounds__(512, 2) void k_gemm256(
    const __hip_bfloat16* __restrict__ X,   // [8192][4096]
    const __hip_bfloat16* __restrict__ W,   // [4096][4096]
    float* __restrict__ out)                // [8192][4096]
{
  extern __shared__ __hip_bfloat16 smem[];  // 131072 B
  __hip_bfloat16* As = smem;                // [2][256*64]
  __hip_bfloat16* Bs = smem + 2 * 16384;

  const int tid  = threadIdx.x;
  const int lane = tid & 63;
  const int wave = tid >> 6;        // 0..7
  const int wm   = wave >> 2;       // 0..1 (M)
  const int wn   = wave & 3;        // 0..3 (N)
  const int lm   = lane & 15;
  const int lq   = lane >> 4;       // 0..3
  const int s_rw = tid >> 3;        // staging row-within-unit 0..63
  const int s_jj = tid & 7;         // staging 16B chunk

  // T1: bijective XCD swizzle (512 blocks, 512 % 8 == 0)
  const int nwg  = gridDim.x * gridDim.y;
  const int cpx  = nwg >> 3;
  const int orig = blockIdx.y * gridDim.x + blockIdx.x;
  const int swz  = (orig & 7) * cpx + (orig >> 3);
  const int bx   = swz % gridDim.x;
  const int by   = swz / gridDim.x;
  const int m0 = by * GBM, n0 = bx * GBN;

  f32x4 acc[8][4] = {};

  // --- staging macros: linear LDS dest (global_load_lds), inverse-swizzled source ---
#define STAGE_A(buf, u, kt) do {                                              \
    int row_ = (u) * 64 + s_rw;                                               \
    int js_  = s_jj ^ (row_ & 7);                                             \
    gload_lds16(X + (size_t)(m0 + row_) * IN_DIM + (kt) * GBK + js_ * 8,      \
                As + (buf) * 16384 + row_ * 64 + s_jj * 8);                   \
  } while (0)
  // B even 32-row chunks (cols read in phases 1-2 of a K-tile)
#define STAGE_BE(buf, half, kt) do {                                          \
    int row_ = (half) * 128 + (s_rw & 31) + ((s_rw & 32) << 1);               \
    int js_  = s_jj ^ (row_ & 7);                                             \
    gload_lds16(W + (size_t)(n0 + row_) * IN_DIM + (kt) * GBK + js_ * 8,      \
                Bs + (buf) * 16384 + row_ * 64 + s_jj * 8);                   \
  } while (0)
  // B odd 32-row chunks (cols read in phases 3-4)
#define STAGE_BL(buf, half, kt) do {                                          \
    int row_ = (half) * 128 + 32 + (s_rw & 31) + ((s_rw & 32) << 1);          \
    int js_  = s_jj ^ (row_ & 7);                                             \
    gload_lds16(W + (size_t)(n0 + row_) * IN_DIM + (kt) * GBK + js_ * 8,      \
                Bs + (buf) * 16384 + row_ * 64 + s_jj * 8);                   \
  } while (0)

#define VM4   do { asm volatile("s_waitcnt vmcnt(4)" ::: "memory"); } while (0)
#define VMNOP do { } while (0)

#define PHASE(QM, QN, BUF, STAGES, DOVM) do {                                 \
    bf16x8 af_[4][2], bf_[2][2];                                              \
    const __hip_bfloat16* Ab_ = As + (BUF) * 16384;                           \
    const __hip_bfloat16* Bb_ = Bs + (BUF) * 16384;                           \
    _Pragma("unroll")                                                         \
    for (int mi2 = 0; mi2 < 4; ++mi2) {                                       \
      int r_ = wm * 128 + (QM) * 64 + mi2 * 16 + lm;                          \
      _Pragma("unroll")                                                       \
      for (int kk = 0; kk < 2; ++kk) {                                        \
        int q_ = kk * 4 + lq;                                                 \
        af_[mi2][kk] = *(const bf16x8*)(Ab_ + r_ * 64 + ((q_ ^ (r_ & 7)) << 3)); \
      }                                                                       \
    }                                                                         \
    _Pragma("unroll")                                                         \
    for (int ni2 = 0; ni2 < 2; ++ni2) {                                       \
      int r_ = wn * 64 + (QN) * 32 + ni2 * 16 + lm;                           \
      _Pragma("unroll")                                                       \
      for (int kk = 0; kk < 2; ++kk) {                                        \
        int q_ = kk * 4 + lq;                                                 \
        bf_[ni2][kk] = *(const bf16x8*)(Bb_ + r_ * 64 + ((q_ ^ (r_ & 7)) << 3)); \
      }                                                                       \
    }                                                                         \
    STAGES;                                                                   \
    __builtin_amdgcn_s_barrier();                                             \
    asm volatile("s_waitcnt lgkmcnt(0)" ::: "memory");                        \
    __builtin_amdgcn_sched_barrier(0);                                        \
    __builtin_amdgcn_s_setprio(1);                                            \
    _Pragma("unroll")                                                         \
    for (int mi2 = 0; mi2 < 4; ++mi2)                                         \
      _Pragma("unroll")                                                       \
      for (int ni2 = 0; ni2 < 2; ++ni2)                                       \
        _Pragma("unroll")                                                     \
        for (int kk = 0; kk < 2; ++kk)                                        \
          acc[(QM) * 4 + mi2][(QN) * 2 + ni2] =                               \
              __builtin_amdgcn_mfma_f32_16x16x32_bf16(                        \
                  af_[mi2][kk], bf_[ni2][kk],                                 \
                  acc[(QM) * 4 + mi2][(QN) * 2 + ni2], 0, 0, 0);              \
    __builtin_amdgcn_s_setprio(0);                                            \
    DOVM;                                                                     \
    __builtin_amdgcn_s_barrier();                                             \
  } while (0)

  // --- prologue: tile 0 fully (8 units), tile 1 partially (BE + A0,A2) ---
  STAGE_BE(0, 0, 0); STAGE_BE(0, 1, 0);
  STAGE_A (0, 0, 0); STAGE_A (0, 2, 0);
  STAGE_BL(0, 0, 0); STAGE_BL(0, 1, 0);
  STAGE_A (0, 1, 0); STAGE_A (0, 3, 0);
  STAGE_BE(1, 0, 1); STAGE_BE(1, 1, 1);
  STAGE_A (1, 0, 1); STAGE_A (1, 2, 1);
  asm volatile("s_waitcnt vmcnt(4)" ::: "memory");   // tile 0 landed
  __builtin_amdgcn_s_barrier();

  // --- main loop: 2 K-tiles per iteration, 8 phases ---
  for (int it = 0; it < NT / 2; ++it) {
    const int t1 = 2 * it + 1;
    const int t2 = (2 * it + 2 < NT) ? 2 * it + 2 : NT - 1;  // dummy re-stage at tail
    const int t3 = (2 * it + 3 < NT) ? 2 * it + 3 : NT - 1;

    PHASE(0, 0, 0, { STAGE_BL(1, 0, t1); STAGE_BL(1, 1, t1); }, VMNOP);  // P1
    PHASE(1, 0, 0, { STAGE_A (1, 1, t1); STAGE_A (1, 3, t1); }, VMNOP);  // P2
    PHASE(0, 1, 0, { STAGE_BE(0, 0, t2); STAGE_BE(0, 1, t2); }, VMNOP);  // P3
    PHASE(1, 1, 0, { STAGE_A (0, 0, t2); STAGE_A (0, 2, t2); }, VM4);    // P4
    PHASE(0, 0, 1, { STAGE_BL(0, 0, t2); STAGE_BL(0, 1, t2); }, VMNOP);  // P5
    PHASE(1, 0, 1, { STAGE_A (0, 1, t2); STAGE_A (0, 3, t2); }, VMNOP);  // P6
    PHASE(0, 1, 1, { STAGE_BE(1, 0, t3); STAGE_BE(1, 1, t3); }, VMNOP);  // P7
    PHASE(1, 1, 1, { STAGE_A (1, 0, t3); STAGE_A (1, 2, t3); }, VM4);    // P8
  }

  // --- epilogue: C/D layout col = lane&15, row = (lane>>4)*4 + reg ---
  #pragma unroll
  for (int mi = 0; mi < 8; ++mi) {
    #pragma unroll
    for (int ni = 0; ni < 4; ++ni) {
      int col   = n0 + wn * 64 + ni * 16 + lm;
      int rbase = m0 + wm * 128 + mi * 16 + lq * 4;
      #pragma unroll
      for (int rg = 0; rg < 4; ++rg) {
        out[(size_t)(rbase + rg) * OUT_DIM + col] = acc[mi][ni][rg];
      }
    }
  }
#undef PHASE
#undef VM4
#undef VMNOP
#undef STAGE_A
#undef STAGE_BE
#undef STAGE_BL
}

extern "C" void kernel_launch(void* const* d_in, const int* in_sizes, int n_in,
                              void* d_out, int out_size, void* d_ws, size_t ws_size,
                              hipStream_t stream) {
  (void)in_sizes; (void)n_in; (void)out_size; (void)ws_size;
  const float* x       = (const float*)d_in[0];
  const int*   trellis = (const int*)d_in[1];
  const float* tlut    = (const float*)d_in[2];
  const float* SU      = (const float*)d_in[3];
  const float* SV      = (const float*)d_in[4];
  float* out = (float*)d_out;

  __hip_bfloat16* Wd = (__hip_bfloat16*)d_ws;                                     // 32 MB
  __hip_bfloat16* Xb = (__hip_bfloat16*)((char*)d_ws + (size_t)32 * 1024 * 1024); // 64 MB

  k_decode_fwht_row<<<4096, 256, 0, stream>>>(trellis, (const float2*)tlut, SU, Wd);
  k_fwht64_lo<<<dim3(64, 64), 256, 0, stream>>>(Wd);
  k_fwht64_hi<<<dim3(64, 64), 256, 0, stream>>>(Wd, SV);
  k_cvt_x<<<16384, 256, 0, stream>>>(x, Xb);

  hipFuncSetAttribute((const void*)k_gemm256,
                      hipFuncAttributeMaxDynamicSharedMemorySize, 131072);
  k_gemm256<<<dim3(IN_DIM / GBN, M_DIM / GBM), 512, 131072, stream>>>(Xb, Wd, out);
}

// Round 5
// 351.259 us; speedup vs baseline: 1.3905x; 1.0724x over previous
//
#include <hip/hip_runtime.h>
#include <hip/hip_bf16.h>
#include <stdint.h>

typedef __bf16 bf16x8 __attribute__((ext_vector_type(8)));
typedef float  f32x4  __attribute__((ext_vector_type(4)));

#define IN_DIM  4096
#define OUT_DIM 4096
#define M_DIM   8192

#define AS1 __attribute__((address_space(1)))
#define AS3 __attribute__((address_space(3)))

static __device__ __forceinline__ void gload_lds16(const void* g, void* l) {
  __builtin_amdgcn_global_load_lds((const AS1 void*)g, (AS3 void*)l, 16, 0, 0);
}

// ---------------- Pass 1: decode trellis + row FWHT(4096) + SU * 1/64 ----------------
__global__ __launch_bounds__(256) void k_decode_fwht_row(
    const int* __restrict__ trellis, const float2* __restrict__ tlut,
    const float* __restrict__ SU, __hip_bfloat16* __restrict__ w)
{
  __shared__ float buf[4096];
  __shared__ int words[128];
  __shared__ float2 lut[1024];
  const int tid = threadIdx.x;
  const int r = blockIdx.x;

  if (tid < 128) words[tid] = trellis[r * 128 + tid];
  for (int i = tid; i < 1024; i += 256) lut[i] = tlut[i];
  __syncthreads();

  {
    const int t  = tid;
    const int wi = t >> 4;
    const int sh = 30 - 2 * (t & 15);
    const unsigned mask = (t < 4) ? ((1u << (2 * t + 2)) - 1u) : 1023u;
    #pragma unroll
    for (int s = 0; s < 8; ++s) {
      unsigned lo = (unsigned)words[s * 16 + wi];
      unsigned hi = wi ? (unsigned)words[s * 16 + wi - 1] : 0u;
      unsigned long long comb = ((unsigned long long)hi << 32) | (unsigned long long)lo;
      unsigned st = ((unsigned)(comb >> sh)) & mask;
      float2 v = lut[st];
      // FWHT stage h=1 folded in-register: pair (2t, 2t+1) -> (x+y, x-y)
      buf[s * 512 + 2 * t]     = v.x + v.y;
      buf[s * 512 + 2 * t + 1] = v.x - v.y;
    }
  }
  __syncthreads();

  for (int h = 2; h < 4096; h <<= 1) {
    #pragma unroll
    for (int q = 0; q < 8; ++q) {
      int b = q * 256 + tid;
      int i = ((b & ~(h - 1)) << 1) | (b & (h - 1));
      float a = buf[i], c = buf[i + h];
      buf[i]     = a + c;
      buf[i + h] = a - c;
    }
    __syncthreads();
  }

  for (int q = 0; q < 16; ++q) {
    int c = q * 256 + tid;
    w[(size_t)r * IN_DIM + c] = __float2bfloat16(buf[c] * SU[c] * 0.015625f);
  }
}

// ---------------- Pass 2a: FWHT64 over row-index low 6 bits (in place) ----------------
__global__ __launch_bounds__(256) void k_fwht64_lo(__hip_bfloat16* __restrict__ w)
{
  __shared__ float tile[64][65];
  const int tid = threadIdx.x;
  const int rb = blockIdx.y, cb = blockIdx.x;

  for (int q = 0; q < 16; ++q) {
    int idx = q * 256 + tid;
    int rr = idx >> 6, cc = idx & 63;
    tile[rr][cc] = __bfloat162float(w[(size_t)(rb * 64 + rr) * IN_DIM + cb * 64 + cc]);
  }
  __syncthreads();

  const int c = tid & 63, qf = tid >> 6;
  for (int h = 1; h < 64; h <<= 1) {
    #pragma unroll
    for (int u = 0; u < 8; ++u) {
      int b = qf * 8 + u;
      int i = ((b & ~(h - 1)) << 1) | (b & (h - 1));
      float a = tile[i][c], d = tile[i + h][c];
      tile[i][c]     = a + d;
      tile[i + h][c] = a - d;
    }
    __syncthreads();
  }

  for (int q = 0; q < 16; ++q) {
    int idx = q * 256 + tid;
    int rr = idx >> 6, cc = idx & 63;
    w[(size_t)(rb * 64 + rr) * IN_DIM + cb * 64 + cc] = __float2bfloat16(tile[rr][cc]);
  }
}

// ---------------- Pass 2b: FWHT64 over row-index high 6 bits + SV * 1/64 ----------------
__global__ __launch_bounds__(256) void k_fwht64_hi(__hip_bfloat16* __restrict__ w,
                                                   const float* __restrict__ SV)
{
  __shared__ float tile[64][65];
  const int tid = threadIdx.x;
  const int r0 = blockIdx.y, cb = blockIdx.x;

  for (int q = 0; q < 16; ++q) {
    int idx = q * 256 + tid;
    int r1 = idx >> 6, cc = idx & 63;
    tile[r1][cc] = __bfloat162float(w[(size_t)(r0 + 64 * r1) * IN_DIM + cb * 64 + cc]);
  }
  __syncthreads();

  const int c = tid & 63, qf = tid >> 6;
  for (int h = 1; h < 64; h <<= 1) {
    #pragma unroll
    for (int u = 0; u < 8; ++u) {
      int b = qf * 8 + u;
      int i = ((b & ~(h - 1)) << 1) | (b & (h - 1));
      float a = tile[i][c], d = tile[i + h][c];
      tile[i][c]     = a + d;
      tile[i + h][c] = a - d;
    }
    __syncthreads();
  }

  for (int q = 0; q < 16; ++q) {
    int idx = q * 256 + tid;
    int r1 = idx >> 6, cc = idx & 63;
    int row = r0 + 64 * r1;
    w[(size_t)row * IN_DIM + cb * 64 + cc] =
        __float2bfloat16(tile[r1][cc] * SV[row] * 0.015625f);
  }
}

// ---------------- x fp32 -> bf16 ----------------
__global__ __launch_bounds__(256) void k_cvt_x(const float* __restrict__ x,
                                               __hip_bfloat16* __restrict__ xb)
{
  size_t i = ((size_t)blockIdx.x * 256 + threadIdx.x) * 8;
  float4 v0 = *(const float4*)(x + i);
  float4 v1 = *(const float4*)(x + i + 4);
  union { __hip_bfloat16 h[8]; uint4 u; } p;
  p.h[0] = __float2bfloat16(v0.x); p.h[1] = __float2bfloat16(v0.y);
  p.h[2] = __float2bfloat16(v0.z); p.h[3] = __float2bfloat16(v0.w);
  p.h[4] = __float2bfloat16(v1.x); p.h[5] = __float2bfloat16(v1.y);
  p.h[6] = __float2bfloat16(v1.z); p.h[7] = __float2bfloat16(v1.w);
  *(uint4*)(xb + i) = p.u;
}

// ================= GEMM: 256x256 tile, 8-phase, fragment-cached (gray order) =========
// Quadrant order per K-tile: (0,0)->(0,1)->(1,1)->(1,0).
// Reads/phase: 12,4,8,4 (28/K-tile vs 48 uncached). Region last-reads:
// A-even@P1, BL@P2, A-odd@P3, BE@P4 -> staging each region >=1 barrier later.
#define GBM 256
#define GBN 256
#define GBK 64
#define NT  (IN_DIM / GBK)   // 64 K-tiles

__global__ __launch_bounds__(512, 2) void k_gemm256(
    const __hip_bfloat16* __restrict__ X,   // [8192][4096]
    const __hip_bfloat16* __restrict__ W,   // [4096][4096]
    float* __restrict__ out)                // [8192][4096]
{
  extern __shared__ __hip_bfloat16 smem[];  // 131072 B
  __hip_bfloat16* As = smem;                // [2][256*64]
  __hip_bfloat16* Bs = smem + 2 * 16384;

  const int tid  = threadIdx.x;
  const int lane = tid & 63;
  const int wave = tid >> 6;        // 0..7
  const int wm   = wave >> 2;       // 0..1 (M)
  const int wn   = wave & 3;        // 0..3 (N)
  const int lm   = lane & 15;
  const int lq   = lane >> 4;       // 0..3
  const int s_rw = tid >> 3;        // staging row-within-unit 0..63
  const int s_jj = tid & 7;         // staging 16B chunk

  // T1: bijective XCD swizzle (512 blocks, 512 % 8 == 0)
  const int nwg  = gridDim.x * gridDim.y;
  const int cpx  = nwg >> 3;
  const int orig = blockIdx.y * gridDim.x + blockIdx.x;
  const int swz  = (orig & 7) * cpx + (orig >> 3);
  const int bx   = swz % gridDim.x;
  const int by   = swz / gridDim.x;
  const int m0 = by * GBM, n0 = bx * GBN;

  f32x4 acc[8][4] = {};
  bf16x8 a_[4][2];      // current A quadrant (even at P1-P2, odd at P3-P4)
  bf16x8 b0_[2][2];     // B QN=0 frags
  bf16x8 b1_[2][2];     // B QN=1 frags

#define STAGE_A(buf, u, kt) do {                                              \
    int row_ = (u) * 64 + s_rw;                                               \
    int js_  = s_jj ^ (row_ & 7);                                             \
    gload_lds16(X + (size_t)(m0 + row_) * IN_DIM + (kt) * GBK + js_ * 8,      \
                As + (buf) * 16384 + row_ * 64 + s_jj * 8);                   \
  } while (0)
#define STAGE_BE(buf, half, kt) do {                                          \
    int row_ = (half) * 128 + (s_rw & 31) + ((s_rw & 32) << 1);               \
    int js_  = s_jj ^ (row_ & 7);                                             \
    gload_lds16(W + (size_t)(n0 + row_) * IN_DIM + (kt) * GBK + js_ * 8,      \
                Bs + (buf) * 16384 + row_ * 64 + s_jj * 8);                   \
  } while (0)
#define STAGE_BL(buf, half, kt) do {                                          \
    int row_ = (half) * 128 + 32 + (s_rw & 31) + ((s_rw & 32) << 1);          \
    int js_  = s_jj ^ (row_ & 7);                                             \
    gload_lds16(W + (size_t)(n0 + row_) * IN_DIM + (kt) * GBK + js_ * 8,      \
                Bs + (buf) * 16384 + row_ * 64 + s_jj * 8);                   \
  } while (0)

#define RD_A(QM, BUF) do {                                                    \
    const __hip_bfloat16* Ab_ = As + (BUF) * 16384;                           \
    _Pragma("unroll")                                                         \
    for (int mi2 = 0; mi2 < 4; ++mi2) {                                       \
      int r_ = wm * 128 + (QM) * 64 + mi2 * 16 + lm;                          \
      _Pragma("unroll")                                                       \
      for (int kk = 0; kk < 2; ++kk) {                                        \
        int q_ = kk * 4 + lq;                                                 \
        a_[mi2][kk] = *(const bf16x8*)(Ab_ + r_ * 64 + ((q_ ^ (r_ & 7)) << 3)); \
      }                                                                       \
    }                                                                         \
  } while (0)
#define RD_B(DST, QN, BUF) do {                                               \
    const __hip_bfloat16* Bb_ = Bs + (BUF) * 16384;                           \
    _Pragma("unroll")                                                         \
    for (int ni2 = 0; ni2 < 2; ++ni2) {                                       \
      int r_ = wn * 64 + (QN) * 32 + ni2 * 16 + lm;                           \
      _Pragma("unroll")                                                       \
      for (int kk = 0; kk < 2; ++kk) {                                        \
        int q_ = kk * 4 + lq;                                                 \
        DST[ni2][kk] = *(const bf16x8*)(Bb_ + r_ * 64 + ((q_ ^ (r_ & 7)) << 3)); \
      }                                                                       \
    }                                                                         \
  } while (0)

#define PH_MID do {                                                           \
    __builtin_amdgcn_s_barrier();                                             \
    asm volatile("s_waitcnt lgkmcnt(0)" ::: "memory");                        \
    __builtin_amdgcn_sched_barrier(0);                                        \
    __builtin_amdgcn_s_setprio(1);                                            \
  } while (0)
#define MFMA_Q(QM, QN, BF) do {                                               \
    _Pragma("unroll")                                                         \
    for (int mi2 = 0; mi2 < 4; ++mi2)                                         \
      _Pragma("unroll")                                                       \
      for (int ni2 = 0; ni2 < 2; ++ni2)                                       \
        _Pragma("unroll")                                                     \
        for (int kk = 0; kk < 2; ++kk)                                        \
          acc[(QM) * 4 + mi2][(QN) * 2 + ni2] =                               \
              __builtin_amdgcn_mfma_f32_16x16x32_bf16(                        \
                  a_[mi2][kk], BF[ni2][kk],                                   \
                  acc[(QM) * 4 + mi2][(QN) * 2 + ni2], 0, 0, 0);              \
  } while (0)
#define VM4   do { asm volatile("s_waitcnt vmcnt(4)" ::: "memory"); } while (0)
#define PH_END do {                                                           \
    __builtin_amdgcn_s_setprio(0);                                            \
    __builtin_amdgcn_s_barrier();                                             \
  } while (0)
#define PH_END_VM do {                                                        \
    __builtin_amdgcn_s_setprio(0);                                            \
    VM4;                                                                      \
    __builtin_amdgcn_s_barrier();                                             \
  } while (0)

  // --- prologue: buf0 <- tile 0 (8 stages); buf1 <- tile 1 partial {A-even, BL} ---
  STAGE_BE(0, 0, 0); STAGE_BE(0, 1, 0);
  STAGE_A (0, 0, 0); STAGE_A (0, 2, 0);
  STAGE_BL(0, 0, 0); STAGE_BL(0, 1, 0);
  STAGE_A (0, 1, 0); STAGE_A (0, 3, 0);
  STAGE_A (1, 0, 1); STAGE_A (1, 2, 1);
  STAGE_BL(1, 0, 1); STAGE_BL(1, 1, 1);
  asm volatile("s_waitcnt vmcnt(4)" ::: "memory");   // tile 0 landed
  __builtin_amdgcn_s_barrier();

  // --- main loop: 2 K-tiles (buf0, buf1) per iteration, 8 phases ---
  for (int it = 0; it < NT / 2; ++it) {
    const int t1 = 2 * it + 1;
    const int t2 = (2 * it + 2 < NT) ? 2 * it + 2 : NT - 1;  // tail: dummy re-stage
    const int t3 = (2 * it + 3 < NT) ? 2 * it + 3 : NT - 1;

    // P1: buf0 quad (0,0)
    RD_A(0, 0); RD_B(b0_, 0, 0);
    STAGE_A(1, 1, t1); STAGE_A(1, 3, t1);
    PH_MID; MFMA_Q(0, 0, b0_); PH_END;
    // P2: buf0 quad (0,1)  [A cached]
    RD_B(b1_, 1, 0);
    STAGE_BE(1, 0, t1); STAGE_BE(1, 1, t1);
    PH_MID; MFMA_Q(0, 1, b1_); PH_END;
    // P3: buf0 quad (1,1)  [B1 cached]
    RD_A(1, 0);
    STAGE_A(0, 0, t2); STAGE_A(0, 2, t2);
    PH_MID; MFMA_Q(1, 1, b1_); PH_END;
    // P4: buf0 quad (1,0)  [A cached]
    RD_B(b0_, 0, 0);
    STAGE_BL(0, 0, t2); STAGE_BL(0, 1, t2);
    PH_MID; MFMA_Q(1, 0, b0_); PH_END_VM;

    // P5: buf1 quad (0,0)
    RD_A(0, 1); RD_B(b0_, 0, 1);
    STAGE_A(0, 1, t2); STAGE_A(0, 3, t2);
    PH_MID; MFMA_Q(0, 0, b0_); PH_END;
    // P6: buf1 quad (0,1)
    RD_B(b1_, 1, 1);
    STAGE_BE(0, 0, t2); STAGE_BE(0, 1, t2);
    PH_MID; MFMA_Q(0, 1, b1_); PH_END;
    // P7: buf1 quad (1,1)
    RD_A(1, 1);
    STAGE_A(1, 0, t3); STAGE_A(1, 2, t3);
    PH_MID; MFMA_Q(1, 1, b1_); PH_END;
    // P8: buf1 quad (1,0)
    RD_B(b0_, 0, 1);
    STAGE_BL(1, 0, t3); STAGE_BL(1, 1, t3);
    PH_MID; MFMA_Q(1, 0, b0_); PH_END_VM;
  }

  // --- epilogue: C/D layout col = lane&15, row = (lane>>4)*4 + reg ---
  #pragma unroll
  for (int mi = 0; mi < 8; ++mi) {
    #pragma unroll
    for (int ni = 0; ni < 4; ++ni) {
      int col   = n0 + wn * 64 + ni * 16 + lm;
      int rbase = m0 + wm * 128 + mi * 16 + lq * 4;
      #pragma unroll
      for (int rg = 0; rg < 4; ++rg) {
        out[(size_t)(rbase + rg) * OUT_DIM + col] = acc[mi][ni][rg];
      }
    }
  }
#undef PH_END_VM
#undef PH_END
#undef VM4
#undef MFMA_Q
#undef PH_MID
#undef RD_B
#undef RD_A
#undef STAGE_BL
#undef STAGE_BE
#undef STAGE_A
}

extern "C" void kernel_launch(void* const* d_in, const int* in_sizes, int n_in,
                              void* d_out, int out_size, void* d_ws, size_t ws_size,
                              hipStream_t stream) {
  (void)in_sizes; (void)n_in; (void)out_size; (void)ws_size;
  const float* x       = (const float*)d_in[0];
  const int*   trellis = (const int*)d_in[1];
  const float* tlut    = (const float*)d_in[2];
  const float* SU      = (const float*)d_in[3];
  const float* SV      = (const float*)d_in[4];
  float* out = (float*)d_out;

  __hip_bfloat16* Wd = (__hip_bfloat16*)d_ws;                                     // 32 MB
  __hip_bfloat16* Xb = (__hip_bfloat16*)((char*)d_ws + (size_t)32 * 1024 * 1024); // 64 MB

  k_decode_fwht_row<<<4096, 256, 0, stream>>>(trellis, (const float2*)tlut, SU, Wd);
  k_fwht64_lo<<<dim3(64, 64), 256, 0, stream>>>(Wd);
  k_fwht64_hi<<<dim3(64, 64), 256, 0, stream>>>(Wd, SV);
  k_cvt_x<<<16384, 256, 0, stream>>>(x, Xb);

  hipFuncSetAttribute((const void*)k_gemm256,
                      hipFuncAttributeMaxDynamicSharedMemorySize, 131072);
  k_gemm256<<<dim3(IN_DIM / GBN, M_DIM / GBM), 512, 131072, stream>>>(Xb, Wd, out);
}